// Round 14
// baseline (267.126 us; speedup 1.0000x reference)
//
#include <hip/hip_runtime.h>
#include <hip/hip_bf16.h>

#define B_   64
#define T_   512
#define N_   14
#define F_   16
#define H_   128
#define G4_  512
#define TCH  64     // timesteps staged per LDS chunk
#define MBLK 4      // sequences per block (4 row-groups of 1)
#define NBLK 224

typedef __attribute__((ext_vector_type(8))) short bfrag;  // 8 bf16
typedef __attribute__((ext_vector_type(4))) float facc;   // fp32 acc
typedef __attribute__((ext_vector_type(4))) int   v4i;    // i8x16 / i32x4

#define L2E   1.4426950408889634f
#define L2E2  2.8853900817779268f

// LDS byte offsets
#define SX   0      // x: [64 tl][4 seq][32 k] bf16 (k>=16 zero) = 16 KB
#define SH   16384  // h8: [2 parity][8 kslice][4 group][16B] = 1 KB
#define LDSZ 17408

__device__ __forceinline__ short f2bf(float f) {
    unsigned u = __builtin_bit_cast(unsigned, f);
    return (short)((u + 0x7FFFu + ((u >> 16) & 1u)) >> 16);
}
__device__ __forceinline__ float bf2f(unsigned short s) {
    return __builtin_bit_cast(float, (unsigned)s << 16);
}
__device__ __forceinline__ unsigned cvt_pk_bf16(float a, float b) {
    unsigned r;
    asm("v_cvt_pk_bf16_f32 %0, %1, %2" : "=v"(r) : "v"(a), "v"(b));
    return r;
}
// guaranteed-native 2^-x (neg folded as input modifier)
__device__ __forceinline__ float ex2n(float x) {
    float r;
    asm("v_exp_f32_e64 %0, -%1" : "=v"(r) : "v"(x));
    return r;
}
// i8 MFMA (validated rounds 6-13)
__device__ __forceinline__ v4i mfma_i8(v4i a, v4i b, v4i c) {
    v4i d;
    asm("v_mfma_i32_16x16x64_i8 %0, %1, %2, %3"
        : "=&v"(d) : "v"(a), "v"(b), "v"(c));
    return d;
}
// lgkm-only barrier: global prefetch loads stay in flight across barriers.
__device__ __forceinline__ void bar() {
    asm volatile("s_waitcnt lgkmcnt(0)" ::: "memory");
    __builtin_amdgcn_s_barrier();
    asm volatile("" ::: "memory");
}
// round-to-nearest-even i8 via magic constant: low byte of (hv*127 + 1.5*2^23)
__device__ __forceinline__ signed char rint8(float hv) {
    const float m = __builtin_fmaf(hv, 127.0f, 12582912.0f);
    return (signed char)__builtin_bit_cast(unsigned, m);
}

// ---------------------------------------------------------------------------
// prep1: per-gate-row max of W_hh -> i8 scale; fused biases; log2e pre-scale
// (2x for the g-gate section) so the epilogue uses native exp2.
// ---------------------------------------------------------------------------
__global__ void prep1_kernel(const float* __restrict__ W_hh,
                             const float* __restrict__ b_ih, const float* __restrict__ b_hh,
                             float* __restrict__ inv127, float* __restrict__ sw,
                             float* __restrict__ bias) {
    const int g = threadIdx.x;            // 0..511
    float mx = 0.0f;
    for (int k = 0; k < H_; ++k) mx = fmaxf(mx, fabsf(W_hh[g * H_ + k]));
    const float sc = (g >= 256 && g < 384) ? L2E2 : L2E;
    inv127[g] = 127.0f / mx;
    sw[g]     = mx * sc * (1.0f / 16129.0f);   // mx/127 * 1/127 * log2e-scale
    bias[g]   = (b_ih[g] + b_hh[g]) * sc;
}

// ---------------------------------------------------------------------------
// prep2: W_hh -> i8 (row-scaled); W_ih -> bf16 (log2e-scaled, K padded 16->32)
// ---------------------------------------------------------------------------
__global__ void prep2_kernel(const float* __restrict__ W_hh, const float* __restrict__ W_ih,
                             const float* __restrict__ inv127,
                             signed char* __restrict__ w8, short* __restrict__ wih_bf) {
    const int i = blockIdx.x * blockDim.x + threadIdx.x;   // 0..65535
    if (i < G4_ * H_)
        w8[i] = (signed char)(int)rintf(W_hh[i] * inv127[i >> 7]);
    if (i < G4_ * 32) {
        const int n = i >> 5, k = i & 31;
        const float sc = (n >= 256 && n < 384) ? L2E2 : L2E;
        wih_bf[i] = (k < F_) ? f2bf(W_ih[n * F_ + k] * sc) : (short)0;
    }
}

// ---------------------------------------------------------------------------
// One timestep for ALL 4 seq-groups; single barrier over 4 waves. Rows
// 4g..4g+3 of the MFMA tile hold group g; wave w owns gate-cols
// [32w,32w+32) as two 16-col groups. Lane (lk,lr) reg0 of colgroup c =
// (group lk, col 32w+16c+lr) -> 2 independent gate chains per lane.
// P = parity (read h[P], write h[P^1]). x-MFMAs run after the h-writes,
// overlapping the barrier wait; xacc parity double-buffer avoids WAR.
// ---------------------------------------------------------------------------
template<int P, bool PREF>
__device__ __forceinline__ void lstm_step(char* lds, int tl,
    const v4i (&B8)[4][2][2], const bfrag (&Bx)[4][2],
    const float (&sw_own)[4][2], const float (&bias_own)[4][2],
    facc (&xacc)[2][4][2], float (&cc)[2],
    int hrd, int xrd, int wb0, int wb1)
{
    bar();
    const char* hb = lds + SH + P * 512;
    const v4i a0 = *(const v4i*)(hb + hrd);          // kslice lk   (k 16lk..)
    const v4i a1 = *(const v4i*)(hb + hrd + 256);    // kslice lk+4 (k 64+16lk)
    bfrag ax;
    if (PREF) ax = *(const bfrag*)(lds + SX + (tl + 1) * 256 + xrd);

    const v4i z4 = (v4i){0, 0, 0, 0};
    v4i p[4][2], r[4][2];
    __builtin_amdgcn_s_setprio(1);
#pragma unroll
    for (int q = 0; q < 4; ++q)
#pragma unroll
        for (int c = 0; c < 2; ++c) p[q][c] = mfma_i8(a0, B8[q][0][c], z4);
#pragma unroll
    for (int q = 0; q < 4; ++q)
#pragma unroll
        for (int c = 0; c < 2; ++c) r[q][c] = mfma_i8(a1, B8[q][1][c], z4);
    __builtin_amdgcn_s_setprio(0);

    // two independent gate chains per lane (colgroups 0,1)
    char* wbuf = lds + SH + (P ^ 1) * 512;
#pragma unroll
    for (int c = 0; c < 2; ++c) {
        float z[4];
#pragma unroll
        for (int q = 0; q < 4; ++q)
            z[q] = (float)(p[q][c][0] + r[q][c][0]) * sw_own[q][c]
                   + (xacc[P][q][c][0] + bias_own[q][c]);
        const float ea = ex2n(z[0]);
        const float ef = ex2n(z[1]);
        const float eo = ex2n(z[3]);
        const float eg = ex2n(fabsf(z[2]));
        const float d1 = (1.0f + ea) * (1.0f + eg);
        const float d2 = 1.0f + ef;
        const float rP = __builtin_amdgcn_rcpf(d1 * d2);   // shared rcp
        const float ig = __builtin_copysignf((1.0f - eg) * (rP * d2), z[2]);
        cc[c] = (rP * d1) * cc[c] + ig;
        const float ec = ex2n(L2E2 * fabsf(cc[c]));
        const float hv = __builtin_copysignf(
            (1.0f - ec) * __builtin_amdgcn_rcpf((1.0f + eo) * (1.0f + ec)), cc[c]);
        *(signed char*)(wbuf + (c ? wb1 : wb0)) = rint8(hv);
    }

    if (PREF) {   // next step's x-part: overlaps the barrier wait
        const facc zf = (facc){0.f, 0.f, 0.f, 0.f};
#pragma unroll
        for (int q = 0; q < 4; ++q)
#pragma unroll
            for (int c = 0; c < 2; ++c)
                xacc[P ^ 1][q][c] =
                    __builtin_amdgcn_mfma_f32_16x16x32_bf16(ax, Bx[q][c], zf, 0, 0, 0);
    }
}

// ---------------------------------------------------------------------------
// LSTM: 224 blocks x 256 thr (4 waves, 1 wave/SIMD); block owns 4 seqs as
// 4 row-groups of the tile. Wave w owns gate-cols [32w,32w+32).
// ---------------------------------------------------------------------------
__global__ __launch_bounds__(256, 1) void lstm_kernel(
    const float* __restrict__ x,            // [B, T, N, F] fp32
    const signed char* __restrict__ w8,     // [512][128] i8
    const short* __restrict__ wih_bf,       // [512][32] bf16
    const float* __restrict__ bias,         // [512] (log2e-scaled)
    const float* __restrict__ sw,           // [512] descale * log2e
    unsigned short* __restrict__ h_out)     // [896][128] bf16
{
    const int m0  = blockIdx.x * MBLK;
    const int tid = threadIdx.x;
    const int w   = tid >> 6, l = tid & 63;
    const int lr  = l & 15, lk = l >> 4;

    __shared__ __align__(16) char lds[LDSZ];

    // ---- loop-invariant register state ----
    v4i   B8[4][2][2];                      // [gate][kslice][colgroup]
    bfrag Bx[4][2];
    float sw_own[4][2], bias_own[4][2];
#pragma unroll
    for (int q = 0; q < 4; ++q) {
#pragma unroll
        for (int c = 0; c < 2; ++c) {
            const int n = q * H_ + 32 * w + 16 * c + lr;
#pragma unroll
            for (int ks = 0; ks < 2; ++ks)
                B8[q][ks][c] = *(const v4i*)(w8 + n * 128 + ks * 64 + lk * 16);
            Bx[q][c] = *(const bfrag*)(wih_bf + n * 32 + lk * 8);
            sw_own[q][c]   = sw[n];
            bias_own[q][c] = bias[n];
        }
    }
#pragma unroll
    for (int q = 0; q < 4; ++q) {          // pin: forbid in-loop remat
#pragma unroll
        for (int c = 0; c < 2; ++c) {
            asm volatile("" : "+v"(B8[q][0][c]));
            asm volatile("" : "+v"(B8[q][1][c]));
            asm volatile("" : "+v"(Bx[q][c]));
        }
    }

    // lane LDS offsets
    // h read (A-frag): row lr -> group lr>>2; layout [kslice][group][16B]
    const int hrd = lk * 64 + (lr >> 2) * 16;
    // x read: [tl][group][32k bf16] -> addr = tl*256 + g*64 + lk*16
    const int xrd = (lr >> 2) * 64 + lk * 16;
    // h write: (group lk, col 32w+16c+lr); kslice = 2w+c
    const int wb0 = (2 * w + 0) * 64 + lk * 16 + lr;
    const int wb1 = (2 * w + 1) * 64 + lk * 16 + lr;

    // staging: thread handles slots tid and tid+256 of (tl, seq, khalf)
    const int skb = tid & 1, sseq = (tid >> 1) & 3, stlA = tid >> 3;
    const int seqg = m0 + sseq;
    const int bb = seqg / N_, nn = seqg % N_;
    const float* xq = x + (((size_t)bb * T_ + stlA) * N_ + nn) * F_ + skb * 8;
    const int sbyteA = SX + stlA * 256 + sseq * 64 + skb * 16;
    const int sbyteB = sbyteA + 32 * 256;           // tl + 32
    const int xoff2  = 32 * N_ * F_;                // +32 timesteps (floats)

    // ---- init: zero LDS (x pad stays 0; h[parity 0] = initial state 0) ----
    for (int i = tid; i < LDSZ / 4; i += 256) ((int*)lds)[i] = 0;
    float4 p0 = *(const float4*)xq,          p1 = *(const float4*)(xq + 4);
    float4 p2 = *(const float4*)(xq + xoff2), p3 = *(const float4*)(xq + xoff2 + 4);

    float cc[2] = {0.f, 0.f};
    facc  xacc[2][4][2];
    bar();

#pragma unroll 1
    for (int chunk = 0; chunk < T_ / TCH; ++chunk) {
        // stage prefetched x chunk (2 slots/thread)
        {
            uint4 oa, ob;
            oa.x = cvt_pk_bf16(p0.x, p0.y); oa.y = cvt_pk_bf16(p0.z, p0.w);
            oa.z = cvt_pk_bf16(p1.x, p1.y); oa.w = cvt_pk_bf16(p1.z, p1.w);
            ob.x = cvt_pk_bf16(p2.x, p2.y); ob.y = cvt_pk_bf16(p2.z, p2.w);
            ob.z = cvt_pk_bf16(p3.x, p3.y); ob.w = cvt_pk_bf16(p3.z, p3.w);
            *(uint4*)(lds + sbyteA) = oa;
            *(uint4*)(lds + sbyteB) = ob;
        }
        if (chunk + 1 < T_ / TCH) {        // next chunk loads stay in flight
            xq += TCH * N_ * F_;
            p0 = *(const float4*)xq;           p1 = *(const float4*)(xq + 4);
            p2 = *(const float4*)(xq + xoff2); p3 = *(const float4*)(xq + xoff2 + 4);
        }
        bar();

        // preamble: xacc[0] for tl=0
        {
            const bfrag ax = *(const bfrag*)(lds + SX + xrd);
            const facc zf = (facc){0.f, 0.f, 0.f, 0.f};
#pragma unroll
            for (int q = 0; q < 4; ++q)
#pragma unroll
                for (int c = 0; c < 2; ++c)
                    xacc[0][q][c] =
                        __builtin_amdgcn_mfma_f32_16x16x32_bf16(ax, Bx[q][c], zf, 0, 0, 0);
        }

#pragma unroll 1
        for (int tl = 0; tl < TCH; tl += 2) {
            lstm_step<0, true>(lds, tl, B8, Bx, sw_own, bias_own, xacc, cc,
                               hrd, xrd, wb0, wb1);
            if (tl + 2 < TCH)
                lstm_step<1, true>(lds, tl + 1, B8, Bx, sw_own, bias_own, xacc, cc,
                                   hrd, xrd, wb0, wb1);
            else
                lstm_step<1, false>(lds, tl + 1, B8, Bx, sw_own, bias_own, xacc, cc,
                                    hrd, xrd, wb0, wb1);
        }
    }
    bar();   // final h writes (parity 0 buf) -> readout

    // readout: h8 -> bf16 (4 seqs x 128 cols; 2 elems/thread)
#pragma unroll
    for (int e0 = 0; e0 < 2; ++e0) {
        const int e = tid + e0 * 256;
        const int g = e >> 7, c = e & 127;
        const int addr = SH + (c >> 4) * 64 + g * 16 + (c & 15);
        const signed char v = *(const signed char*)(lds + addr);
        h_out[(size_t)(m0 + g) * H_ + c] = f2bf((float)v * (1.0f / 127.0f));
    }
}

// ---------------------------------------------------------------------------
// Head kernel: one block per batch element b. GCN + linears + sigmoid.
// ---------------------------------------------------------------------------
__global__ __launch_bounds__(256) void head_kernel(
    const float* __restrict__ adj,
    const float* __restrict__ W_gcn, const float* __restrict__ b_gcn,
    const float* __restrict__ W_out, const float* __restrict__ b_out,
    const float* __restrict__ W_lin1, const float* __restrict__ b_lin1,
    const unsigned short* __restrict__ h_in,   // [896][128] bf16
    float* __restrict__ out)                   // [B, 28]
{
    const int b   = blockIdx.x;
    const int tid = threadIdx.x;

    __shared__ float s_A[N_][N_];
    __shared__ float s_d[N_];
    __shared__ float s_h[N_][H_];
    __shared__ float s_xg[N_][H_];
    __shared__ float s_g1[N_][64];
    __shared__ float s_s[N_];

    for (int idx = tid; idx < N_ * H_; idx += 256)
        s_h[idx >> 7][idx & 127] = bf2f(h_in[(size_t)b * N_ * H_ + idx]);

    if (tid < N_) {
        float sum = 0.0f;
        for (int j = 0; j < N_; ++j)
            sum += adj[tid * N_ + j] + (tid == j ? 1.0f : 0.0f);
        s_d[tid] = rsqrtf(sum);
    }
    __syncthreads();

    if (tid < N_ * N_) {
        const int i = tid / N_, j = tid % N_;
        const float a = adj[i * N_ + j] + (i == j ? 1.0f : 0.0f);
        s_A[i][j] = s_d[i] * a * s_d[j];
    }
    __syncthreads();

    for (int idx = tid; idx < N_ * H_; idx += 256) {
        const int i = idx >> 7, k = idx & 127;
        float acc = 0.0f;
#pragma unroll
        for (int j = 0; j < N_; ++j) acc += s_A[i][j] * s_h[j][k];
        s_xg[i][k] = acc;
    }
    __syncthreads();

    for (int idx = tid; idx < N_ * 64; idx += 256) {
        const int i = idx >> 6, q = idx & 63;
        float a0 = 0.f, a1 = 0.f, a2 = 0.f, a3 = 0.f;
#pragma unroll
        for (int k = 0; k < H_; k += 4) {
            a0 += s_xg[i][k+0] * W_gcn[q * H_ + k+0];
            a1 += s_xg[i][k+1] * W_gcn[q * H_ + k+1];
            a2 += s_xg[i][k+2] * W_gcn[q * H_ + k+2];
            a3 += s_xg[i][k+3] * W_gcn[q * H_ + k+3];
        }
        const float acc = b_gcn[q] + ((a0 + a1) + (a2 + a3));
        s_g1[i][q] = fmaxf(acc, 0.0f);
    }
    __syncthreads();

    if (tid < N_) {
        float acc = b_out[0];
#pragma unroll
        for (int q = 0; q < 64; ++q) acc += s_g1[tid][q] * W_out[q];
        s_s[tid] = acc;
    }
    __syncthreads();

    if (tid < 28) {
        float acc = b_lin1[tid];
#pragma unroll
        for (int i = 0; i < N_; ++i) acc += s_s[i] * W_lin1[tid * N_ + i];
        out[b * 28 + tid] = 1.0f / (1.0f + __expf(-acc));
    }
}

extern "C" void kernel_launch(void* const* d_in, const int* in_sizes, int n_in,
                              void* d_out, int out_size, void* d_ws, size_t ws_size,
                              hipStream_t stream) {
    const float* x      = (const float*)d_in[0];
    const float* adj    = (const float*)d_in[1];
    const float* W_ih   = (const float*)d_in[2];
    const float* W_hh   = (const float*)d_in[3];
    const float* b_ih   = (const float*)d_in[4];
    const float* b_hh   = (const float*)d_in[5];
    const float* W_gcn  = (const float*)d_in[6];
    const float* b_gcn  = (const float*)d_in[7];
    const float* W_out  = (const float*)d_in[8];
    const float* b_out  = (const float*)d_in[9];
    const float* W_lin1 = (const float*)d_in[10];
    const float* b_lin1 = (const float*)d_in[11];
    float* out = (float*)d_out;

    // workspace layout (bytes): total 333824
    char* ws = (char*)d_ws;
    signed char*    w8     = (signed char*)(ws);              // 512*128   =  65536
    short*          wih_bf = (short*)(ws + 65536);            // 512*32*2  =  32768
    float*          bias   = (float*)(ws + 98304);            // 512*4     =   2048
    float*          sw     = (float*)(ws + 100352);           // 512*4     =   2048
    float*          inv127 = (float*)(ws + 102400);           // 512*4     =   2048
    unsigned short* h_last = (unsigned short*)(ws + 104448);  // 896*128*2 = 229376

    prep1_kernel<<<1, 512, 0, stream>>>(W_hh, b_ih, b_hh, inv127, sw, bias);
    prep2_kernel<<<128, 512, 0, stream>>>(W_hh, W_ih, inv127, w8, wih_bf);
    lstm_kernel<<<NBLK, 256, 0, stream>>>(x, w8, wih_bf, bias, sw, h_last);
    head_kernel<<<B_, 256, 0, stream>>>(adj, W_gcn, b_gcn, W_out, b_out,
                                        W_lin1, b_lin1, h_last, out);
}